// Round 6
// baseline (67.066 us; speedup 1.0000x reference)
//
#include <hip/hip_runtime.h>
#include <hip/hip_bf16.h>
#include <math.h>

#define NROWS 8192
#define DIM 128
#define BM 128                        // rows per block tile
#define BN 128                        // cols per inner tile
#define CS 8                          // column slabs
#define COLS_PER_SLAB (NROWS / CS)    // 1024
#define CT_ITERS (COLS_PER_SLAB / BN) // 8
#define RS (NROWS / BM)               // 64
#define NGB 64                        // k_gsum blocks

typedef __attribute__((ext_vector_type(8))) short bf16x8;
typedef __attribute__((ext_vector_type(4))) float f32x4;

__device__ __forceinline__ float bf2f(ushort u) {
  return __uint_as_float(((unsigned)u) << 16);
}

// ---------------- label histogram (single block, LDS sub-hists, NO global atomics)
// also zeroes losssum
__global__ __launch_bounds__(1024) void k_hist(const int* __restrict__ lab,
                                               int* __restrict__ hist,
                                               float* __restrict__ losssum) {
  __shared__ int sh[16][16];
  const int t = threadIdx.x;
  const int w = t >> 6;
  if ((t & 63) < 16) sh[w][t & 63] = 0;
  __syncthreads();
#pragma unroll
  for (int it = 0; it < NROWS / 1024; ++it)
    atomicAdd(&sh[w][lab[t + it * 1024]], 1);
  __syncthreads();
  if (t < 10) {
    int s = 0;
#pragma unroll
    for (int x = 0; x < 16; ++x) s += sh[x][t];
    hist[t] = s;
  }
  if (t == 10) losssum[0] = 0.f;
}

// ---------------- normalize rows -> bf16 ----------------
__global__ __launch_bounds__(256) void k_norm(const float* __restrict__ f,
                                              __hip_bfloat16* __restrict__ fnb) {
  int wave = threadIdx.x >> 6;
  int lane = threadIdx.x & 63;
  int row = blockIdx.x * 4 + wave;
  const float* src = f + (size_t)row * DIM;
  float v0 = src[lane];
  float v1 = src[lane + 64];
  float ss = v0 * v0 + v1 * v1;
#pragma unroll
  for (int o = 32; o > 0; o >>= 1) ss += __shfl_down(ss, o);
  ss = __shfl(ss, 0);
  float inv = 1.0f / fmaxf(sqrtf(ss), 1e-8f);
  __hip_bfloat16* dst = fnb + (size_t)row * DIM;
  dst[lane] = __float2bfloat16(v0 * inv);
  dst[lane + 64] = __float2bfloat16(v1 * inv);
}

// ---------------- per-class feature sums (partials, no global atomics) ----------------
// block b handles rows [b*128, +128); pg[b][c][d] = sum of fn[row][d] for lab==c
__global__ __launch_bounds__(256) void k_gsum(const ushort* __restrict__ fnb,
                                              const int* __restrict__ lab,
                                              float* __restrict__ pg) {
  __shared__ float g[2][10][DIM];  // 10 KB
  const int t = threadIdx.x;
  const int rg = t >> 7;       // 0..1
  const int d = t & 127;
#pragma unroll
  for (int c = 0; c < 10; ++c) g[rg][c][d] = 0.f;
  __syncthreads();
  const int base = blockIdx.x * 128 + rg * 64;
#pragma unroll 4
  for (int r = 0; r < 64; ++r) {
    int row = base + r;
    int c = lab[row];
    g[rg][c][d] += bf2f(fnb[(size_t)row * DIM + d]);  // (rg,d) exclusive: no race
  }
  __syncthreads();
  if (rg == 0) {
#pragma unroll
    for (int c = 0; c < 10; ++c)
      pg[((size_t)blockIdx.x * 10 + c) * DIM + d] = g[0][c][d] + g[1][c][d];
  }
}

// ---------------- single MFMA pass ----------------
// 512 threads = 8 waves (2 row-halves x 4 col-quarters). Per-wave 64x32 C-tile.
// Per row accumulate: totE = sum_all exp(2s), posE = sum_pos exp(2s).
__global__ __launch_bounds__(512, 4) void k_main(
    const ushort* __restrict__ fnb, const int* __restrict__ lab,
    float* __restrict__ ptot, float* __restrict__ ppos) {
  __shared__ char lds[BM * 256 + BN * 256];  // A (32KB) + B (32KB), swizzled
  char* Alds = lds;
  char* Blds = lds + BM * 256;

  const int t = threadIdx.x;
  const int lane = t & 63;
  const int w = t >> 6;
  const int wm = w >> 2;  // 0..1  (row half)
  const int wn = w & 3;   // 0..3  (col quarter)
  const int g = lane >> 4;
  const int cs = blockIdx.x;
  const int i0 = blockIdx.y * BM;

  // ---- stage A once (rows i0..i0+127), XOR-swizzled ----
  {
    const int4* src = reinterpret_cast<const int4*>(fnb + (size_t)i0 * DIM);
#pragma unroll
    for (int it = 0; it < 4; ++it) {
      int q = t + 512 * it;       // 0..2047 16B-chunks
      int row = q >> 4, c = q & 15;
      int4 v = src[q];
      *reinterpret_cast<int4*>(Alds + row * 256 + ((c << 4) ^ ((row & 7) << 4))) = v;
    }
  }

  // labels for this thread's C rows: rl = wm*64 + m*16 + g*4 + r
  int lr[4][4];
#pragma unroll
  for (int m = 0; m < 4; ++m)
#pragma unroll
    for (int r = 0; r < 4; ++r)
      lr[m][r] = lab[i0 + wm * 64 + m * 16 + g * 4 + r];

  float a_tot[4][4] = {}, a_pos[4][4] = {};

  for (int ct = 0; ct < CT_ITERS; ++ct) {
    const int j0 = cs * COLS_PER_SLAB + ct * BN;
    __syncthreads();  // protect Blds from previous iteration's readers
    {
      const int4* src = reinterpret_cast<const int4*>(fnb + (size_t)j0 * DIM);
#pragma unroll
      for (int it = 0; it < 4; ++it) {
        int q = t + 512 * it;
        int row = q >> 4, c = q & 15;
        int4 v = src[q];
        *reinterpret_cast<int4*>(Blds + row * 256 + ((c << 4) ^ ((row & 7) << 4))) = v;
      }
    }
    __syncthreads();

    f32x4 acc[4][2];
#pragma unroll
    for (int m = 0; m < 4; ++m)
#pragma unroll
      for (int n = 0; n < 2; ++n) acc[m][n] = (f32x4){0.f, 0.f, 0.f, 0.f};

#pragma unroll
    for (int ks = 0; ks < 4; ++ks) {
      const int kb = ks * 64 + (g << 4);  // 16B chunk within 256B row
      bf16x8 af[4], bf[2];
#pragma unroll
      for (int m = 0; m < 4; ++m) {
        int r = wm * 64 + m * 16 + (lane & 15);
        af[m] = *reinterpret_cast<const bf16x8*>(Alds + r * 256 + (kb ^ ((r & 7) << 4)));
      }
#pragma unroll
      for (int n = 0; n < 2; ++n) {
        int r = wn * 32 + n * 16 + (lane & 15);
        bf[n] = *reinterpret_cast<const bf16x8*>(Blds + r * 256 + (kb ^ ((r & 7) << 4)));
      }
#pragma unroll
      for (int m = 0; m < 4; ++m)
#pragma unroll
        for (int n = 0; n < 2; ++n)
          acc[m][n] = __builtin_amdgcn_mfma_f32_16x16x32_bf16(af[m], bf[n], acc[m][n], 0, 0, 0);
    }

    // epilogue: per-row totE (unconditional) + posE (masked)
#pragma unroll
    for (int n = 0; n < 2; ++n) {
      const int lc = lab[j0 + wn * 32 + n * 16 + (lane & 15)];
#pragma unroll
      for (int m = 0; m < 4; ++m)
#pragma unroll
        for (int r = 0; r < 4; ++r) {
          float s = acc[m][n][r];           // cos sim (sim = 2*s)
          float E = __expf(2.0f * s);
          a_tot[m][r] += E;
          a_pos[m][r] += (lr[m][r] == lc) ? E : 0.f;
        }
    }
  }

  // reduce across the 16 lanes (cols) of each row group
#pragma unroll
  for (int m = 0; m < 4; ++m)
#pragma unroll
    for (int r = 0; r < 4; ++r)
#pragma unroll
      for (int off = 8; off > 0; off >>= 1) {
        a_tot[m][r] += __shfl_xor(a_tot[m][r], off);
        a_pos[m][r] += __shfl_xor(a_pos[m][r], off);
      }

  __syncthreads();  // done with tiles; reuse LDS as reduction scratch
  float* red = reinterpret_cast<float*>(lds);  // [128][4 wn][2]
  if ((lane & 15) == 0) {
#pragma unroll
    for (int m = 0; m < 4; ++m)
#pragma unroll
      for (int r = 0; r < 4; ++r) {
        int rl = wm * 64 + m * 16 + g * 4 + r;
        red[(rl * 4 + wn) * 2 + 0] = a_tot[m][r];
        red[(rl * 4 + wn) * 2 + 1] = a_pos[m][r];
      }
  }
  __syncthreads();
  if (wn == 0 && (lane & 15) == 0) {
#pragma unroll
    for (int m = 0; m < 4; ++m)
#pragma unroll
      for (int r = 0; r < 4; ++r) {
        int rl = wm * 64 + m * 16 + g * 4 + r;
        int row = i0 + rl;
        float st = 0.f, sp = 0.f;
#pragma unroll
        for (int x = 0; x < 4; ++x) {
          st += red[(rl * 4 + x) * 2 + 0];
          sp += red[(rl * 4 + x) * 2 + 1];
        }
        ptot[cs * NROWS + row] = st;
        ppos[cs * NROWS + row] = sp;
      }
  }
}

// ---------------- per-row finalize + global sum ----------------
__global__ __launch_bounds__(1024) void k_rowfinal(
    const float* __restrict__ ptot, const float* __restrict__ ppos,
    const int* __restrict__ lab, const int* __restrict__ hist,
    float* __restrict__ losssum) {
  __shared__ float sred[1024];
  int i = blockIdx.x * 1024 + threadIdx.x;
  float st = 0.f, sp = 0.f;
#pragma unroll
  for (int cs = 0; cs < CS; ++cs) {
    st += ptot[cs * NROWS + i];
    sp += ppos[cs * NROWS + i];
  }
  float cnt = (float)hist[lab[i]];
  float negtot = st - sp + cnt;  // negsum + positives' exp(0)=1 each
  // sum over positives of [log(negtot) + log1p(E/negtot)] ~= cnt*log(negtot) + posE/negtot
  float li = cnt * logf(negtot) + sp / negtot;
  sred[threadIdx.x] = li;
  __syncthreads();
  for (int s2 = 512; s2 > 0; s2 >>= 1) {
    if (threadIdx.x < s2) sred[threadIdx.x] += sred[threadIdx.x + s2];
    __syncthreads();
  }
  if (threadIdx.x == 0) atomicAdd(losssum, sred[0]);
}

// ---------------- output: fold in -2*sum_c ||g_c||^2, divide by num_pos ----------------
__global__ __launch_bounds__(1024) void k_out(const float* __restrict__ losssum,
                                              const int* __restrict__ hist,
                                              const float* __restrict__ pg,
                                              float* __restrict__ out) {
  __shared__ float sred[1024];
  const int t = threadIdx.x;
  float s2 = 0.f;
  for (int cell = t; cell < 10 * DIM; cell += 1024) {
    float gg = 0.f;
#pragma unroll 8
    for (int b = 0; b < NGB; ++b) gg += pg[(size_t)b * 10 * DIM + cell];
    s2 += gg * gg;
  }
  sred[t] = s2;
  __syncthreads();
  for (int s = 512; s > 0; s >>= 1) {
    if (t < s) sred[t] += sred[t + s];
    __syncthreads();
  }
  if (t == 0) {
    double np = 0.0;
    for (int c = 0; c < 10; ++c) np += (double)hist[c] * (double)hist[c];
    // loss = (sum_i [cnt*log(negtot)+posE/negtot] - 2*sum_c ||g_c||^2) / num_pos
    out[0] = (float)(((double)losssum[0] - 2.0 * (double)sred[0]) / np);
  }
}

extern "C" void kernel_launch(void* const* d_in, const int* in_sizes, int n_in,
                              void* d_out, int out_size, void* d_ws, size_t ws_size,
                              hipStream_t stream) {
  const float* feat = (const float*)d_in[0];
  const int* lab = (const int*)d_in[1];
  float* out = (float*)d_out;

  char* ws = (char*)d_ws;
  __hip_bfloat16* fnb = (__hip_bfloat16*)ws;               // 2 MiB
  size_t off = (size_t)NROWS * DIM * 2;
  float* ptot = (float*)(ws + off); off += (size_t)CS * NROWS * 4;   // 256 KiB
  float* ppos = (float*)(ws + off); off += (size_t)CS * NROWS * 4;
  float* pg   = (float*)(ws + off); off += (size_t)NGB * 10 * DIM * 4;  // 320 KiB
  int* hist = (int*)(ws + off);     off += 64;
  float* losssum = (float*)(ws + off);

  k_hist<<<1, 1024, 0, stream>>>(lab, hist, losssum);
  k_norm<<<NROWS / 4, 256, 0, stream>>>(feat, fnb);
  k_gsum<<<NGB, 256, 0, stream>>>((const ushort*)fnb, lab, pg);
  dim3 grid(CS, RS);
  k_main<<<grid, 512, 0, stream>>>((const ushort*)fnb, lab, ptot, ppos);
  k_rowfinal<<<NROWS / 1024, 1024, 0, stream>>>(ptot, ppos, lab, hist, losssum);
  k_out<<<1, 1024, 0, stream>>>(losssum, hist, pg, out);
}

// Round 7
// 65.557 us; speedup vs baseline: 1.0230x; 1.0230x over previous
//
#include <hip/hip_runtime.h>
#include <hip/hip_bf16.h>
#include <math.h>

#define NROWS 8192
#define DIM 128
#define CS 16                         // column slabs
#define COLS_PER_SLAB (NROWS / CS)    // 512
#define CT_ITERS (COLS_PER_SLAB / 32) // 16

typedef __attribute__((ext_vector_type(8))) short bf16x8;
typedef __attribute__((ext_vector_type(4))) float f32x4;

// ---------------- label histogram (single block, LDS sub-hists, NO global atomics)
// also zeroes losssum
__global__ __launch_bounds__(1024) void k_hist(const int* __restrict__ lab,
                                               int* __restrict__ hist,
                                               float* __restrict__ losssum) {
  __shared__ int sh[16][16];
  const int t = threadIdx.x;
  const int w = t >> 6;
  if ((t & 63) < 16) sh[w][t & 63] = 0;
  __syncthreads();
#pragma unroll
  for (int it = 0; it < NROWS / 1024; ++it)
    atomicAdd(&sh[w][lab[t + it * 1024]], 1);
  __syncthreads();
  if (t < 10) {
    int s = 0;
#pragma unroll
    for (int x = 0; x < 16; ++x) s += sh[x][t];
    hist[t] = s;
  }
  if (t == 10) losssum[0] = 0.f;
}

// ---------------- normalize rows -> bf16 ----------------
__global__ __launch_bounds__(256) void k_norm(const float* __restrict__ f,
                                              __hip_bfloat16* __restrict__ fnb) {
  int wave = threadIdx.x >> 6;
  int lane = threadIdx.x & 63;
  int row = blockIdx.x * 4 + wave;
  const float* src = f + (size_t)row * DIM;
  float v0 = src[lane];
  float v1 = src[lane + 64];
  float ss = v0 * v0 + v1 * v1;
#pragma unroll
  for (int o = 32; o > 0; o >>= 1) ss += __shfl_down(ss, o);
  ss = __shfl(ss, 0);
  float inv = 1.0f / fmaxf(sqrtf(ss), 1e-8f);
  __hip_bfloat16* dst = fnb + (size_t)row * DIM;
  dst[lane] = __float2bfloat16(v0 * inv);
  dst[lane + 64] = __float2bfloat16(v1 * inv);
}

// ---------------- single MFMA pass, LDS-free ----------------
// 2048 waves total: wave gid -> cs = gid>>7 (col slab of 512), i0 = (gid&127)*64.
// A rows (64) live in registers for the whole kernel; B fragments stream from L2.
// Per row accumulate: totE = sum_all exp(2s), posE = sum_pos exp(2s), posS = sum_pos s.
__global__ __launch_bounds__(256, 2) void k_main(
    const ushort* __restrict__ fnb, const int* __restrict__ lab,
    float* __restrict__ ptot, float* __restrict__ ppos, float* __restrict__ psim) {
  const int lane = threadIdx.x & 63;
  const int g = lane >> 4;      // k-chunk group
  const int li16 = lane & 15;   // row/col within 16-tile
  const int gid = blockIdx.x * 4 + (threadIdx.x >> 6);
  const int cs = gid >> 7;
  const int i0 = (gid & 127) * 64;

  // ---- A fragments in registers: rows i0 + m*16 + li16, k = ks*32 + g*8 ----
  bf16x8 af[4][4];
#pragma unroll
  for (int m = 0; m < 4; ++m) {
    const ushort* arow = fnb + (size_t)(i0 + m * 16 + li16) * DIM + g * 8;
#pragma unroll
    for (int ks = 0; ks < 4; ++ks)
      af[m][ks] = *reinterpret_cast<const bf16x8*>(arow + ks * 32);
  }

  // labels of this thread's C rows: row = i0 + m*16 + g*4 + r
  int lr[4][4];
#pragma unroll
  for (int m = 0; m < 4; ++m)
#pragma unroll
    for (int r = 0; r < 4; ++r)
      lr[m][r] = lab[i0 + m * 16 + g * 4 + r];

  float a_tot[4][4] = {}, a_pos[4][4] = {}, a_sim[4][4] = {};

  const int jslab = cs * COLS_PER_SLAB;
  for (int ct = 0; ct < CT_ITERS; ++ct) {
    const int jb = jslab + ct * 32;
    int lc[2];
    lc[0] = lab[jb + li16];
    lc[1] = lab[jb + 16 + li16];

    bf16x8 bf[2][4];
#pragma unroll
    for (int n = 0; n < 2; ++n) {
      const ushort* brow = fnb + (size_t)(jb + n * 16 + li16) * DIM + g * 8;
#pragma unroll
      for (int ks = 0; ks < 4; ++ks)
        bf[n][ks] = *reinterpret_cast<const bf16x8*>(brow + ks * 32);
    }

    f32x4 acc[4][2];
#pragma unroll
    for (int m = 0; m < 4; ++m)
#pragma unroll
      for (int n = 0; n < 2; ++n) acc[m][n] = (f32x4){0.f, 0.f, 0.f, 0.f};

#pragma unroll
    for (int ks = 0; ks < 4; ++ks)
#pragma unroll
      for (int m = 0; m < 4; ++m)
#pragma unroll
        for (int n = 0; n < 2; ++n)
          acc[m][n] = __builtin_amdgcn_mfma_f32_16x16x32_bf16(af[m][ks], bf[n][ks],
                                                              acc[m][n], 0, 0, 0);

    // epilogue (C layout: col = lane&15, row = g*4 + r)
#pragma unroll
    for (int n = 0; n < 2; ++n)
#pragma unroll
      for (int m = 0; m < 4; ++m)
#pragma unroll
        for (int r = 0; r < 4; ++r) {
          float s = acc[m][n][r];            // cos sim (sim = 2*s)
          float E = __expf(2.0f * s);
          bool pos = (lr[m][r] == lc[n]);
          a_tot[m][r] += E;
          a_pos[m][r] += pos ? E : 0.f;
          a_sim[m][r] += pos ? s : 0.f;
        }
  }

  // reduce across the 16 lanes (cols) of each row group
#pragma unroll
  for (int m = 0; m < 4; ++m)
#pragma unroll
    for (int r = 0; r < 4; ++r)
#pragma unroll
      for (int off = 8; off > 0; off >>= 1) {
        a_tot[m][r] += __shfl_xor(a_tot[m][r], off);
        a_pos[m][r] += __shfl_xor(a_pos[m][r], off);
        a_sim[m][r] += __shfl_xor(a_sim[m][r], off);
      }

  if (li16 == 0) {
#pragma unroll
    for (int m = 0; m < 4; ++m)
#pragma unroll
      for (int r = 0; r < 4; ++r) {
        int row = i0 + m * 16 + g * 4 + r;
        ptot[(size_t)cs * NROWS + row] = a_tot[m][r];
        ppos[(size_t)cs * NROWS + row] = a_pos[m][r];
        psim[(size_t)cs * NROWS + row] = a_sim[m][r];
      }
  }
}

// ---------------- per-row finalize + global sum ----------------
__global__ __launch_bounds__(1024) void k_rowfinal(
    const float* __restrict__ ptot, const float* __restrict__ ppos,
    const float* __restrict__ psim,
    const int* __restrict__ lab, const int* __restrict__ hist,
    float* __restrict__ losssum) {
  __shared__ float sred[1024];
  int i = blockIdx.x * 1024 + threadIdx.x;
  float st = 0.f, sp = 0.f, sa = 0.f;
#pragma unroll
  for (int cs = 0; cs < CS; ++cs) {
    st += ptot[(size_t)cs * NROWS + i];
    sp += ppos[(size_t)cs * NROWS + i];
    sa += psim[(size_t)cs * NROWS + i];
  }
  float cnt = (float)hist[lab[i]];
  float negtot = st - sp + cnt;  // negatives' E + positives' exp(0)=1 each
  // sum over positives of [log(negtot) + log1p(E/negtot) - sim]
  //   ~= cnt*log(negtot) + posE/negtot - 2*posS   (log1p 2nd order < 3e-7 on loss)
  float li = cnt * logf(negtot) + sp / negtot - 2.f * sa;
  sred[threadIdx.x] = li;
  __syncthreads();
  for (int s2 = 512; s2 > 0; s2 >>= 1) {
    if (threadIdx.x < s2) sred[threadIdx.x] += sred[threadIdx.x + s2];
    __syncthreads();
  }
  if (threadIdx.x == 0) atomicAdd(losssum, sred[0]);
}

// ---------------- output ----------------
__global__ void k_out(const float* __restrict__ losssum, const int* __restrict__ hist,
                      float* __restrict__ out) {
  if (threadIdx.x == 0) {
    double np = 0.0;
    for (int c = 0; c < 10; ++c) np += (double)hist[c] * (double)hist[c];
    out[0] = (float)((double)losssum[0] / np);
  }
}

extern "C" void kernel_launch(void* const* d_in, const int* in_sizes, int n_in,
                              void* d_out, int out_size, void* d_ws, size_t ws_size,
                              hipStream_t stream) {
  const float* feat = (const float*)d_in[0];
  const int* lab = (const int*)d_in[1];
  float* out = (float*)d_out;

  char* ws = (char*)d_ws;
  __hip_bfloat16* fnb = (__hip_bfloat16*)ws;               // 2 MiB
  size_t off = (size_t)NROWS * DIM * 2;
  float* ptot = (float*)(ws + off); off += (size_t)CS * NROWS * 4;   // 512 KiB
  float* ppos = (float*)(ws + off); off += (size_t)CS * NROWS * 4;
  float* psim = (float*)(ws + off); off += (size_t)CS * NROWS * 4;
  int* hist = (int*)(ws + off);     off += 64;
  float* losssum = (float*)(ws + off);

  k_norm<<<NROWS / 4, 256, 0, stream>>>(feat, fnb);
  k_hist<<<1, 1024, 0, stream>>>(lab, hist, losssum);
  k_main<<<512, 256, 0, stream>>>((const ushort*)fnb, lab, ptot, ppos, psim);
  k_rowfinal<<<NROWS / 1024, 1024, 0, stream>>>(ptot, ppos, psim, lab, hist, losssum);
  k_out<<<1, 64, 0, stream>>>(losssum, hist, out);
}